// Round 2
// baseline (677.267 us; speedup 1.0000x reference)
//
#include <hip/hip_runtime.h>

typedef unsigned short u16;
typedef short s16x8 __attribute__((ext_vector_type(8)));
typedef float f32x4 __attribute__((ext_vector_type(4)));
typedef float f32x2 __attribute__((ext_vector_type(2)));

#define NNODES 55296
#define NEDGES 221184
#define ROWS   110592   // B * NNODES
#define NBLK_SCAN 216   // NNODES / 256

__device__ __forceinline__ u16 f2bf(float f) {
    union { float f; unsigned u; } v; v.f = f;
    unsigned r = (v.u + 0x7fffu + ((v.u >> 16) & 1u)) >> 16;
    return (u16)r;
}
__device__ __forceinline__ float bf2f(u16 u) {
    return __uint_as_float(((unsigned)u) << 16);
}

// ---------------------------------------------------------------------------
// Edge sorting by dst: histogram -> hierarchical exclusive scan -> scatter.
// One-time cost per launch; pays for itself 3x in the step loop.
// ---------------------------------------------------------------------------
__global__ __launch_bounds__(256) void hist_kernel(
    const int* __restrict__ edst, int* __restrict__ cnt)
{
    int i = blockIdx.x * 256 + threadIdx.x;
    atomicAdd(&cnt[edst[i]], 1);
}

__global__ __launch_bounds__(256) void scan1_kernel(
    const int* __restrict__ cnt, int* __restrict__ exc, int* __restrict__ bsum)
{
    __shared__ int s[256];
    int t = threadIdx.x, g = blockIdx.x * 256 + t;
    int v = cnt[g];
    s[t] = v; __syncthreads();
#pragma unroll
    for (int d = 1; d < 256; d <<= 1) {
        int x = (t >= d) ? s[t - d] : 0;
        __syncthreads();
        s[t] += x;
        __syncthreads();
    }
    exc[g] = s[t] - v;
    if (t == 255) bsum[blockIdx.x] = s[255];
}

__global__ __launch_bounds__(256) void scan2_kernel(
    const int* __restrict__ bsum, int* __restrict__ bofs)
{
    __shared__ int s[256];
    int t = threadIdx.x;
    int v = (t < NBLK_SCAN) ? bsum[t] : 0;
    s[t] = v; __syncthreads();
#pragma unroll
    for (int d = 1; d < 256; d <<= 1) {
        int x = (t >= d) ? s[t - d] : 0;
        __syncthreads();
        s[t] += x;
        __syncthreads();
    }
    if (t < NBLK_SCAN) bofs[t] = s[t] - v;
}

__global__ __launch_bounds__(256) void scan3_kernel(
    const int* __restrict__ exc, const int* __restrict__ bofs, int* __restrict__ rowstart)
{
    int g = blockIdx.x * 256 + threadIdx.x;
    rowstart[g] = exc[g] + bofs[blockIdx.x];
    if (g == 0) rowstart[NNODES] = NEDGES;
}

__global__ __launch_bounds__(256) void scatter_kernel(
    const int* __restrict__ edst, const int* __restrict__ esrc,
    const int* __restrict__ rowstart, int* __restrict__ cursor,
    int* __restrict__ perm, int* __restrict__ esrcp, int* __restrict__ edstp)
{
    int i = blockIdx.x * 256 + threadIdx.x;
    int d = edst[i];
    int pos = rowstart[d] + atomicAdd(&cursor[d], 1);
    perm[pos] = i;
    esrcp[pos] = esrc[i];
    edstp[pos] = d;
}

// ---------------------------------------------------------------------------
// Pack a [32 x ncols] fp32 matrix (optionally transposed source [ncols x 32])
// into MFMA B-fragment layout.
// ---------------------------------------------------------------------------
__global__ __launch_bounds__(256) void pack_bfrag(
    const float* __restrict__ src, u16* __restrict__ dst_hi, u16* __restrict__ dst_lo,
    int ntiles, int ncols, int trans)
{
    int idx = blockIdx.x * 256 + threadIdx.x;
    if (idx >= ntiles * 512) return;
    int t = idx >> 9, rr = idx & 511, lane = rr >> 3, j = rr & 7;
    int k = (lane >> 4) * 8 + j;
    int n = t * 16 + (lane & 15);
    float v = trans ? src[n * 32 + k] : src[k * ncols + n];
    u16 hb = f2bf(v);
    dst_hi[idx] = hb;
    if (dst_lo) dst_lo[idx] = f2bf(v - bf2f(hb));
}

// ---------------------------------------------------------------------------
// Edge MLP layer 1, writing rbf in DST-SORTED edge order (reads er via perm).
// ---------------------------------------------------------------------------
__global__ __launch_bounds__(256) void edgemlp_kernel(
    const float* __restrict__ er, const float* __restrict__ ew1,
    const float* __restrict__ eb1, const int* __restrict__ perm,
    u16* __restrict__ rbf)
{
    __shared__ float er_lds[32];
    __shared__ float w_lds[128];
    __shared__ float b_lds[32];
    int tid = threadIdx.x;
    int e8 = blockIdx.x * 8;   // sorted position base
    if (tid < 32) {
        int e = perm[e8 + (tid >> 2)];
        er_lds[tid] = er[e * 4 + (tid & 3)];
    }
    else if (tid < 160) w_lds[tid - 32] = ew1[tid - 32];
    else if (tid < 192) b_lds[tid - 160] = eb1[tid - 160];
    __syncthreads();
    int el = tid >> 5, o = tid & 31;
    const float* e4 = er_lds + el * 4;
    float v = b_lds[o] + e4[0] * w_lds[o] + e4[1] * w_lds[32 + o]
                       + e4[2] * w_lds[64 + o] + e4[3] * w_lds[96 + o];
    rbf[(e8 + el) * 32 + o] = f2bf(fmaxf(v, 0.f));
}

// ---------------------------------------------------------------------------
// Node projection (unchanged): h0 = relu(x@pw1+pb1)@pw2+pb2.
// ---------------------------------------------------------------------------
__global__ __launch_bounds__(256) void nodeproj_kernel(
    const float* __restrict__ x,
    const u16* __restrict__ pw1h, const u16* __restrict__ pw1l, const float* __restrict__ pb1,
    const u16* __restrict__ pw2h, const u16* __restrict__ pw2l, const float* __restrict__ pb2,
    float* __restrict__ st_f32, u16* __restrict__ st_hi, u16* __restrict__ st_lo)
{
    __shared__ alignas(16) u16 t_hi[4][512];
    __shared__ alignas(16) u16 t_lo[4][512];
    int tid = threadIdx.x, wave = tid >> 6, lane = tid & 63;
    int quad = lane >> 4, col = lane & 15;
    int row0 = (blockIdx.x * 4 + wave) * 16;

    const float* xp = x + (row0 + col) * 32 + quad * 8;
    f32x4 xv0 = *(const f32x4*)(xp), xv1 = *(const f32x4*)(xp + 4);
    s16x8 ah, al;
#pragma unroll
    for (int i = 0; i < 4; ++i) {
        u16 h0 = f2bf(xv0[i]); ah[i] = (short)h0; al[i] = (short)f2bf(xv0[i] - bf2f(h0));
        u16 h1 = f2bf(xv1[i]); ah[4+i] = (short)h1; al[4+i] = (short)f2bf(xv1[i] - bf2f(h1));
    }
#pragma unroll
    for (int t = 0; t < 2; ++t) {
        s16x8 bh = *(const s16x8*)(pw1h + t * 512 + lane * 8);
        s16x8 bl = *(const s16x8*)(pw1l + t * 512 + lane * 8);
        f32x4 acc = {0,0,0,0};
        acc = __builtin_amdgcn_mfma_f32_16x16x32_bf16(al, bh, acc, 0,0,0);
        acc = __builtin_amdgcn_mfma_f32_16x16x32_bf16(ah, bl, acc, 0,0,0);
        acc = __builtin_amdgcn_mfma_f32_16x16x32_bf16(ah, bh, acc, 0,0,0);
        float bias = pb1[t * 16 + col];
#pragma unroll
        for (int r = 0; r < 4; ++r) {
            float v = fmaxf(acc[r] + bias, 0.f);
            u16 hb = f2bf(v);
            int idx = (quad * 4 + r) * 32 + t * 16 + col;
            t_hi[wave][idx] = hb;
            t_lo[wave][idx] = f2bf(v - bf2f(hb));
        }
    }
    __syncthreads();
    s16x8 th = *(const s16x8*)(&t_hi[wave][col * 32 + quad * 8]);
    s16x8 tl = *(const s16x8*)(&t_lo[wave][col * 32 + quad * 8]);
#pragma unroll
    for (int t = 0; t < 2; ++t) {
        s16x8 bh = *(const s16x8*)(pw2h + t * 512 + lane * 8);
        s16x8 bl = *(const s16x8*)(pw2l + t * 512 + lane * 8);
        f32x4 acc = {0,0,0,0};
        acc = __builtin_amdgcn_mfma_f32_16x16x32_bf16(tl, bh, acc, 0,0,0);
        acc = __builtin_amdgcn_mfma_f32_16x16x32_bf16(th, bl, acc, 0,0,0);
        acc = __builtin_amdgcn_mfma_f32_16x16x32_bf16(th, bh, acc, 0,0,0);
        float bias = pb2[t * 16 + col];
#pragma unroll
        for (int r = 0; r < 4; ++r) {
            float v = acc[r] + bias;
            int row = row0 + quad * 4 + r;
            int o = t * 16 + col;
            st_f32[row * 32 + o] = v;
            u16 hb = f2bf(v);
            st_hi[row * 32 + o] = hb;
            st_lo[row * 32 + o] = f2bf(v - bf2f(hb));
        }
    }
}

// ---------------------------------------------------------------------------
// Message kernel v2: atomic-free. Each wave OWNS 16 dst nodes; edges are
// dst-sorted, processed in chunks of 16; messages accumulate into a per-wave
// LDS tile via ds_add_f32; final plain coalesced store to agg (no memset).
// Padded chunk slots contribute exactly 0 (ns zeroed, rbf pad zeroed).
// ---------------------------------------------------------------------------
__global__ __launch_bounds__(256) void msg_kernel(
    const u16* __restrict__ rbf, const u16* __restrict__ ew2f,
    const float* __restrict__ eb2, const float* __restrict__ state,
    const int* __restrict__ esrcp, const int* __restrict__ edstp,
    const int* __restrict__ rowstart,
    float* __restrict__ agg)
{
    __shared__ alignas(16) float eb2_lds[1024];
    __shared__ alignas(16) float ns_lds[4][16 * 68];    // [wave][e*68 + b*32 + h]
    __shared__ alignas(16) float agg_lds[4][16 * 68];   // [wave][node*68 + b*32 + o]
    int tid = threadIdx.x;
    {   // stage eb2 (block-wide)
        *(f32x4*)(eb2_lds + tid * 4) = *(const f32x4*)(eb2 + tid * 4);
    }
    int wave = tid >> 6, lane = tid & 63;
    int quad = lane >> 4, col = lane & 15;
    int n0 = (blockIdx.x * 4 + wave) * 16;
    int base = rowstart[n0], end = rowstart[n0 + 16];

    float* ag = &agg_lds[wave][0];
    for (int i = lane; i < 16 * 68; i += 64) ag[i] = 0.f;
    __syncthreads();   // eb2 visible block-wide

    const float* nsw = &ns_lds[wave][0];
    for (int p0 = base; p0 < end; p0 += 16) {
        // stage gathered node features for this chunk's 16 edges (zeros if pad)
        {
            int el = lane >> 2, part = lane & 3;
            int b = part >> 1, half = part & 1;
            int p = p0 + el;
            float* dp = &ns_lds[wave][el * 68 + b * 32 + half * 16];
            if (p < end) {
                int src = esrcp[p];
                const float* sp = state + (size_t)(b * NNODES + src) * 32 + half * 16;
                *(f32x4*)(dp + 0)  = *(const f32x4*)(sp + 0);
                *(f32x4*)(dp + 4)  = *(const f32x4*)(sp + 4);
                *(f32x4*)(dp + 8)  = *(const f32x4*)(sp + 8);
                *(f32x4*)(dp + 12) = *(const f32x4*)(sp + 12);
            } else {
                f32x4 z = {0,0,0,0};
                *(f32x4*)(dp + 0) = z; *(f32x4*)(dp + 4) = z;
                *(f32x4*)(dp + 8) = z; *(f32x4*)(dp + 12) = z;
            }
        }
        int dl[4];
#pragma unroll
        for (int r = 0; r < 4; ++r) {
            int pr = p0 + quad * 4 + r;        // edstp alloc is padded; clamp result
            int d = edstp[pr] - n0;
            dl[r] = d < 0 ? 0 : (d > 15 ? 15 : d);
        }
        // A fragment: 16 edge rows x K=32 (sorted-order rbf, coalesced)
        s16x8 afrag = *(const s16x8*)(rbf + (size_t)(p0 + col) * 32 + quad * 8);

        float msg[2][2][4] = {};   // [b][o-half][reg]
#pragma unroll 4
        for (int hh = 0; hh < 16; ++hh) {
            int h0 = hh * 2, h1 = hh * 2 + 1;
            s16x8 b0 = *(const s16x8*)(ew2f + (4 * hh + 0) * 512 + lane * 8);
            s16x8 b1 = *(const s16x8*)(ew2f + (4 * hh + 1) * 512 + lane * 8);
            s16x8 b2 = *(const s16x8*)(ew2f + (4 * hh + 2) * 512 + lane * 8);
            s16x8 b3 = *(const s16x8*)(ew2f + (4 * hh + 3) * 512 + lane * 8);
            f32x4 z = {0,0,0,0};
            f32x4 d0 = __builtin_amdgcn_mfma_f32_16x16x32_bf16(afrag, b0, z, 0,0,0);
            f32x4 d1 = __builtin_amdgcn_mfma_f32_16x16x32_bf16(afrag, b1, z, 0,0,0);
            f32x4 d2 = __builtin_amdgcn_mfma_f32_16x16x32_bf16(afrag, b2, z, 0,0,0);
            f32x4 d3 = __builtin_amdgcn_mfma_f32_16x16x32_bf16(afrag, b3, z, 0,0,0);
            float e00 = eb2_lds[h0 * 32 + col],      e01 = eb2_lds[h0 * 32 + 16 + col];
            float e10 = eb2_lds[h1 * 32 + col],      e11 = eb2_lds[h1 * 32 + 16 + col];
#pragma unroll
            for (int r = 0; r < 4; ++r) {
                int e = quad * 4 + r;
                f32x2 n0v = *(const f32x2*)(nsw + e * 68 + 0 * 32 + h0);
                f32x2 n1v = *(const f32x2*)(nsw + e * 68 + 1 * 32 + h0);
                float w00 = d0[r] + e00, w01 = d1[r] + e01;
                float w10 = d2[r] + e10, w11 = d3[r] + e11;
                msg[0][0][r] += n0v.x * w00 + n0v.y * w10;
                msg[0][1][r] += n0v.x * w01 + n0v.y * w11;
                msg[1][0][r] += n1v.x * w00 + n1v.y * w10;
                msg[1][1][r] += n1v.x * w01 + n1v.y * w11;
            }
        }
        // flush chunk messages into per-wave LDS node accumulator
#pragma unroll
        for (int r = 0; r < 4; ++r) {
            float* abase = ag + dl[r] * 68;
            atomicAdd(abase + col,           msg[0][0][r]);
            atomicAdd(abase + 16 + col,      msg[0][1][r]);
            atomicAdd(abase + 32 + col,      msg[1][0][r]);
            atomicAdd(abase + 48 + col,      msg[1][1][r]);
        }
    }
    __syncthreads();
    // store: 16 nodes x 2 batches x 32 floats, plain coalesced writes
    for (int i = lane; i < 256; i += 64) {
        int node = i >> 4, q = i & 15;
        f32x4 v = *(f32x4*)(ag + node * 68 + q * 4);
        int b = q >> 3, o = (q & 7) * 4;
        *(f32x4*)(agg + ((size_t)(b * NNODES) + n0 + node) * 32 + o) = v;
    }
}

// ---------------------------------------------------------------------------
// GRU step (unchanged).
// ---------------------------------------------------------------------------
__global__ __launch_bounds__(256) void gru_kernel(
    const float* __restrict__ agg, const float* __restrict__ conv_b,
    const float* __restrict__ st_f32, const u16* __restrict__ st_hi, const u16* __restrict__ st_lo,
    const u16* __restrict__ wihh, const u16* __restrict__ wihl,
    const u16* __restrict__ whhh, const u16* __restrict__ whhl,
    const float* __restrict__ b_ih, const float* __restrict__ b_hh,
    float* __restrict__ out_f32, u16* __restrict__ out_hi, u16* __restrict__ out_lo)
{
    int tid = threadIdx.x, wave = tid >> 6, lane = tid & 63;
    int quad = lane >> 4, col = lane & 15;
    int row0 = (blockIdx.x * 4 + wave) * 16;

    const float* ap = agg + (row0 + col) * 32 + quad * 8;
    f32x4 av0 = *(const f32x4*)(ap), av1 = *(const f32x4*)(ap + 4);
    const float* cb = conv_b + quad * 8;
    f32x4 cb0 = *(const f32x4*)(cb), cb1 = *(const f32x4*)(cb + 4);
    s16x8 anh, anl;
#pragma unroll
    for (int i = 0; i < 4; ++i) {
        float v0 = fmaxf(av0[i] + cb0[i], 0.f);
        float v1 = fmaxf(av1[i] + cb1[i], 0.f);
        u16 h0 = f2bf(v0); anh[i] = (short)h0;   anl[i] = (short)f2bf(v0 - bf2f(h0));
        u16 h1 = f2bf(v1); anh[4+i] = (short)h1; anl[4+i] = (short)f2bf(v1 - bf2f(h1));
    }
    s16x8 ahh = *(const s16x8*)(st_hi + (row0 + col) * 32 + quad * 8);
    s16x8 ahl = *(const s16x8*)(st_lo + (row0 + col) * 32 + quad * 8);

    f32x4 gx[6], gh[6];
#pragma unroll
    for (int t = 0; t < 6; ++t) {
        s16x8 bh = *(const s16x8*)(wihh + t * 512 + lane * 8);
        s16x8 bl = *(const s16x8*)(wihl + t * 512 + lane * 8);
        f32x4 acc = {0,0,0,0};
        acc = __builtin_amdgcn_mfma_f32_16x16x32_bf16(anl, bh, acc, 0,0,0);
        acc = __builtin_amdgcn_mfma_f32_16x16x32_bf16(anh, bl, acc, 0,0,0);
        acc = __builtin_amdgcn_mfma_f32_16x16x32_bf16(anh, bh, acc, 0,0,0);
        gx[t] = acc;
        s16x8 ch = *(const s16x8*)(whhh + t * 512 + lane * 8);
        s16x8 cl = *(const s16x8*)(whhl + t * 512 + lane * 8);
        f32x4 acc2 = {0,0,0,0};
        acc2 = __builtin_amdgcn_mfma_f32_16x16x32_bf16(ahl, ch, acc2, 0,0,0);
        acc2 = __builtin_amdgcn_mfma_f32_16x16x32_bf16(ahh, cl, acc2, 0,0,0);
        acc2 = __builtin_amdgcn_mfma_f32_16x16x32_bf16(ahh, ch, acc2, 0,0,0);
        gh[t] = acc2;
    }
    float bihv[6], bhhv[6];
#pragma unroll
    for (int t = 0; t < 6; ++t) { bihv[t] = b_ih[t * 16 + col]; bhhv[t] = b_hh[t * 16 + col]; }

#pragma unroll
    for (int r = 0; r < 4; ++r) {
        int row = row0 + quad * 4 + r;
#pragma unroll
        for (int oh = 0; oh < 2; ++oh) {
            int o = oh * 16 + col;
            float hid = st_f32[row * 32 + o];
            float sr = (gx[oh][r] + bihv[oh]) + (gh[oh][r] + bhhv[oh]);
            float sz = (gx[2+oh][r] + bihv[2+oh]) + (gh[2+oh][r] + bhhv[2+oh]);
            float gxn = gx[4+oh][r] + bihv[4+oh];
            float ghn = gh[4+oh][r] + bhhv[4+oh];
            float rr = 1.f / (1.f + __expf(-sr));
            float zz = 1.f / (1.f + __expf(-sz));
            float narg = gxn + rr * ghn;
            float ex = __expf(2.f * narg);
            float nn = (ex - 1.f) / (ex + 1.f);
            float hnew = (1.f - zz) * nn + zz * hid;
            out_f32[row * 32 + o] = hnew;
            u16 hb = f2bf(hnew);
            out_hi[row * 32 + o] = hb;
            out_lo[row * 32 + o] = f2bf(hnew - bf2f(hb));
        }
    }
}

// ---------------------------------------------------------------------------
extern "C" void kernel_launch(void* const* d_in, const int* in_sizes, int n_in,
                              void* d_out, int out_size, void* d_ws, size_t ws_size,
                              hipStream_t stream)
{
    const float* x      = (const float*)d_in[0];
    const float* er     = (const float*)d_in[1];
    const float* pw1    = (const float*)d_in[2];
    const float* pb1    = (const float*)d_in[3];
    const float* pw2    = (const float*)d_in[4];
    const float* pb2    = (const float*)d_in[5];
    const float* ew1    = (const float*)d_in[6];
    const float* eb1    = (const float*)d_in[7];
    const float* ew2    = (const float*)d_in[8];
    const float* eb2    = (const float*)d_in[9];
    const float* conv_b = (const float*)d_in[10];
    const float* wih    = (const float*)d_in[11];
    const float* whh    = (const float*)d_in[12];
    const float* bih    = (const float*)d_in[13];
    const float* bhh    = (const float*)d_in[14];
    const int*   esrc   = (const int*)d_in[15];
    const int*   edst   = (const int*)d_in[16];
    float* out = (float*)d_out;

    char* ws = (char*)d_ws;
    size_t off = 0;
    auto alloc = [&](size_t bytes) -> void* {
        void* p = ws + off;
        off = (off + bytes + 255) & ~(size_t)255;
        return p;
    };
    u16*   rbf    = (u16*)  alloc((size_t)(NEDGES + 16) * 32 * 2);
    float* st_f32 = (float*)alloc((size_t)ROWS * 32 * 4);
    u16*   st_hi  = (u16*)  alloc((size_t)ROWS * 32 * 2);
    u16*   st_lo  = (u16*)  alloc((size_t)ROWS * 32 * 2);
    float* agg    = (float*)alloc((size_t)ROWS * 32 * 4);
    u16*   ew2f   = (u16*)  alloc(64 * 512 * 2);
    u16*   pw1h   = (u16*)  alloc(2 * 512 * 2);
    u16*   pw1l   = (u16*)  alloc(2 * 512 * 2);
    u16*   pw2h   = (u16*)  alloc(2 * 512 * 2);
    u16*   pw2l   = (u16*)  alloc(2 * 512 * 2);
    u16*   wihhf  = (u16*)  alloc(6 * 512 * 2);
    u16*   wihlf  = (u16*)  alloc(6 * 512 * 2);
    u16*   whhhf  = (u16*)  alloc(6 * 512 * 2);
    u16*   whhlf  = (u16*)  alloc(6 * 512 * 2);
    // sort infrastructure
    int*   cnt      = (int*)alloc((size_t)NNODES * 4);
    int*   cursor   = (int*)alloc((size_t)NNODES * 4);
    int*   exc      = (int*)alloc((size_t)NNODES * 4);
    int*   bsum     = (int*)alloc(NBLK_SCAN * 4);
    int*   bofs     = (int*)alloc(NBLK_SCAN * 4);
    int*   rowstart = (int*)alloc((size_t)(NNODES + 1) * 4);
    int*   perm     = (int*)alloc((size_t)NEDGES * 4);
    int*   esrcp    = (int*)alloc((size_t)(NEDGES + 16) * 4);
    int*   edstp    = (int*)alloc((size_t)(NEDGES + 16) * 4);
    (void)in_sizes; (void)n_in; (void)out_size; (void)ws_size;

    // --- one-time: sort edges by dst ---
    hipMemsetAsync(cnt, 0, (size_t)NNODES * 4, stream);
    hipMemsetAsync(cursor, 0, (size_t)NNODES * 4, stream);
    hipMemsetAsync(rbf + (size_t)NEDGES * 32, 0, 16 * 32 * 2, stream);  // zero pad edges
    hist_kernel<<<NEDGES / 256, 256, 0, stream>>>(edst, cnt);
    scan1_kernel<<<NBLK_SCAN, 256, 0, stream>>>(cnt, exc, bsum);
    scan2_kernel<<<1, 256, 0, stream>>>(bsum, bofs);
    scan3_kernel<<<NBLK_SCAN, 256, 0, stream>>>(exc, bofs, rowstart);
    scatter_kernel<<<NEDGES / 256, 256, 0, stream>>>(edst, esrc, rowstart, cursor,
                                                     perm, esrcp, edstp);

    pack_bfrag<<<128, 256, 0, stream>>>(ew2, ew2f, (u16*)nullptr, 64, 1024, 0);
    pack_bfrag<<<4,   256, 0, stream>>>(pw1, pw1h, pw1l, 2, 32, 0);
    pack_bfrag<<<4,   256, 0, stream>>>(pw2, pw2h, pw2l, 2, 32, 0);
    pack_bfrag<<<12,  256, 0, stream>>>(wih, wihhf, wihlf, 6, 96, 1);
    pack_bfrag<<<12,  256, 0, stream>>>(whh, whhhf, whhlf, 6, 96, 1);

    edgemlp_kernel<<<NEDGES / 8, 256, 0, stream>>>(er, ew1, eb1, perm, rbf);
    nodeproj_kernel<<<ROWS / 64, 256, 0, stream>>>(x, pw1h, pw1l, pb1, pw2h, pw2l, pb2,
                                                   st_f32, st_hi, st_lo);
    for (int s = 0; s < 3; ++s) {
        msg_kernel<<<NNODES / 64, 256, 0, stream>>>(rbf, ew2f, eb2, st_f32,
                                                    esrcp, edstp, rowstart, agg);
        float* of = (s == 2) ? out : st_f32;
        gru_kernel<<<ROWS / 64, 256, 0, stream>>>(agg, conv_b, st_f32, st_hi, st_lo,
                                                  wihhf, wihlf, whhhf, whhlf, bih, bhh,
                                                  of, st_hi, st_lo);
    }
}

// Round 3
// 386.745 us; speedup vs baseline: 1.7512x; 1.7512x over previous
//
#include <hip/hip_runtime.h>

typedef unsigned short u16;
typedef short s16x8 __attribute__((ext_vector_type(8)));
typedef float f32x4 __attribute__((ext_vector_type(4)));
typedef float f32x2 __attribute__((ext_vector_type(2)));

#define NNODES 55296
#define NEDGES 221184
#define ROWS   110592   // B * NNODES
#define NBLK_SCAN 216   // NNODES / 256

__device__ __forceinline__ u16 f2bf(float f) {
    union { float f; unsigned u; } v; v.f = f;
    unsigned r = (v.u + 0x7fffu + ((v.u >> 16) & 1u)) >> 16;
    return (u16)r;
}
__device__ __forceinline__ float bf2f(u16 u) {
    return __uint_as_float(((unsigned)u) << 16);
}

// ---------------------------------------------------------------------------
// Edge sorting by dst: histogram -> hierarchical exclusive scan -> scatter.
// One-time cost per launch; measured ~free in round 2.
// ---------------------------------------------------------------------------
__global__ __launch_bounds__(256) void hist_kernel(
    const int* __restrict__ edst, int* __restrict__ cnt)
{
    int i = blockIdx.x * 256 + threadIdx.x;
    atomicAdd(&cnt[edst[i]], 1);
}

__global__ __launch_bounds__(256) void scan1_kernel(
    const int* __restrict__ cnt, int* __restrict__ exc, int* __restrict__ bsum)
{
    __shared__ int s[256];
    int t = threadIdx.x, g = blockIdx.x * 256 + t;
    int v = cnt[g];
    s[t] = v; __syncthreads();
#pragma unroll
    for (int d = 1; d < 256; d <<= 1) {
        int x = (t >= d) ? s[t - d] : 0;
        __syncthreads();
        s[t] += x;
        __syncthreads();
    }
    exc[g] = s[t] - v;
    if (t == 255) bsum[blockIdx.x] = s[255];
}

__global__ __launch_bounds__(256) void scan2_kernel(
    const int* __restrict__ bsum, int* __restrict__ bofs)
{
    __shared__ int s[256];
    int t = threadIdx.x;
    int v = (t < NBLK_SCAN) ? bsum[t] : 0;
    s[t] = v; __syncthreads();
#pragma unroll
    for (int d = 1; d < 256; d <<= 1) {
        int x = (t >= d) ? s[t - d] : 0;
        __syncthreads();
        s[t] += x;
        __syncthreads();
    }
    if (t < NBLK_SCAN) bofs[t] = s[t] - v;
}

__global__ __launch_bounds__(256) void scan3_kernel(
    const int* __restrict__ exc, const int* __restrict__ bofs, int* __restrict__ rowstart)
{
    int g = blockIdx.x * 256 + threadIdx.x;
    rowstart[g] = exc[g] + bofs[blockIdx.x];
    if (g == 0) rowstart[NNODES] = NEDGES;
}

__global__ __launch_bounds__(256) void scatter_kernel(
    const int* __restrict__ edst, const int* __restrict__ esrc,
    const int* __restrict__ rowstart, int* __restrict__ cursor,
    int* __restrict__ perm, int* __restrict__ esrcp, int* __restrict__ edstp)
{
    int i = blockIdx.x * 256 + threadIdx.x;
    int d = edst[i];
    int pos = rowstart[d] + atomicAdd(&cursor[d], 1);
    perm[pos] = i;
    esrcp[pos] = esrc[i];
    edstp[pos] = d;
}

// ---------------------------------------------------------------------------
// Pack a [32 x ncols] fp32 matrix (optionally transposed source [ncols x 32])
// into MFMA B-fragment layout.
// ---------------------------------------------------------------------------
__global__ __launch_bounds__(256) void pack_bfrag(
    const float* __restrict__ src, u16* __restrict__ dst_hi, u16* __restrict__ dst_lo,
    int ntiles, int ncols, int trans)
{
    int idx = blockIdx.x * 256 + threadIdx.x;
    if (idx >= ntiles * 512) return;
    int t = idx >> 9, rr = idx & 511, lane = rr >> 3, j = rr & 7;
    int k = (lane >> 4) * 8 + j;
    int n = t * 16 + (lane & 15);
    float v = trans ? src[n * 32 + k] : src[k * ncols + n];
    u16 hb = f2bf(v);
    dst_hi[idx] = hb;
    if (dst_lo) dst_lo[idx] = f2bf(v - bf2f(hb));
}

// ---------------------------------------------------------------------------
// Edge MLP layer 1, writing rbf in DST-SORTED edge order (reads er via perm).
// ---------------------------------------------------------------------------
__global__ __launch_bounds__(256) void edgemlp_kernel(
    const float* __restrict__ er, const float* __restrict__ ew1,
    const float* __restrict__ eb1, const int* __restrict__ perm,
    u16* __restrict__ rbf)
{
    __shared__ float er_lds[32];
    __shared__ float w_lds[128];
    __shared__ float b_lds[32];
    int tid = threadIdx.x;
    int e8 = blockIdx.x * 8;   // sorted position base
    if (tid < 32) {
        int e = perm[e8 + (tid >> 2)];
        er_lds[tid] = er[e * 4 + (tid & 3)];
    }
    else if (tid < 160) w_lds[tid - 32] = ew1[tid - 32];
    else if (tid < 192) b_lds[tid - 160] = eb1[tid - 160];
    __syncthreads();
    int el = tid >> 5, o = tid & 31;
    const float* e4 = er_lds + el * 4;
    float v = b_lds[o] + e4[0] * w_lds[o] + e4[1] * w_lds[32 + o]
                       + e4[2] * w_lds[64 + o] + e4[3] * w_lds[96 + o];
    rbf[(e8 + el) * 32 + o] = f2bf(fmaxf(v, 0.f));
}

// ---------------------------------------------------------------------------
// Node projection (unchanged): h0 = relu(x@pw1+pb1)@pw2+pb2.
// ---------------------------------------------------------------------------
__global__ __launch_bounds__(256) void nodeproj_kernel(
    const float* __restrict__ x,
    const u16* __restrict__ pw1h, const u16* __restrict__ pw1l, const float* __restrict__ pb1,
    const u16* __restrict__ pw2h, const u16* __restrict__ pw2l, const float* __restrict__ pb2,
    float* __restrict__ st_f32, u16* __restrict__ st_hi, u16* __restrict__ st_lo)
{
    __shared__ alignas(16) u16 t_hi[4][512];
    __shared__ alignas(16) u16 t_lo[4][512];
    int tid = threadIdx.x, wave = tid >> 6, lane = tid & 63;
    int quad = lane >> 4, col = lane & 15;
    int row0 = (blockIdx.x * 4 + wave) * 16;

    const float* xp = x + (row0 + col) * 32 + quad * 8;
    f32x4 xv0 = *(const f32x4*)(xp), xv1 = *(const f32x4*)(xp + 4);
    s16x8 ah, al;
#pragma unroll
    for (int i = 0; i < 4; ++i) {
        u16 h0 = f2bf(xv0[i]); ah[i] = (short)h0; al[i] = (short)f2bf(xv0[i] - bf2f(h0));
        u16 h1 = f2bf(xv1[i]); ah[4+i] = (short)h1; al[4+i] = (short)f2bf(xv1[i] - bf2f(h1));
    }
#pragma unroll
    for (int t = 0; t < 2; ++t) {
        s16x8 bh = *(const s16x8*)(pw1h + t * 512 + lane * 8);
        s16x8 bl = *(const s16x8*)(pw1l + t * 512 + lane * 8);
        f32x4 acc = {0,0,0,0};
        acc = __builtin_amdgcn_mfma_f32_16x16x32_bf16(al, bh, acc, 0,0,0);
        acc = __builtin_amdgcn_mfma_f32_16x16x32_bf16(ah, bl, acc, 0,0,0);
        acc = __builtin_amdgcn_mfma_f32_16x16x32_bf16(ah, bh, acc, 0,0,0);
        float bias = pb1[t * 16 + col];
#pragma unroll
        for (int r = 0; r < 4; ++r) {
            float v = fmaxf(acc[r] + bias, 0.f);
            u16 hb = f2bf(v);
            int idx = (quad * 4 + r) * 32 + t * 16 + col;
            t_hi[wave][idx] = hb;
            t_lo[wave][idx] = f2bf(v - bf2f(hb));
        }
    }
    __syncthreads();
    s16x8 th = *(const s16x8*)(&t_hi[wave][col * 32 + quad * 8]);
    s16x8 tl = *(const s16x8*)(&t_lo[wave][col * 32 + quad * 8]);
#pragma unroll
    for (int t = 0; t < 2; ++t) {
        s16x8 bh = *(const s16x8*)(pw2h + t * 512 + lane * 8);
        s16x8 bl = *(const s16x8*)(pw2l + t * 512 + lane * 8);
        f32x4 acc = {0,0,0,0};
        acc = __builtin_amdgcn_mfma_f32_16x16x32_bf16(tl, bh, acc, 0,0,0);
        acc = __builtin_amdgcn_mfma_f32_16x16x32_bf16(th, bl, acc, 0,0,0);
        acc = __builtin_amdgcn_mfma_f32_16x16x32_bf16(th, bh, acc, 0,0,0);
        float bias = pb2[t * 16 + col];
#pragma unroll
        for (int r = 0; r < 4; ++r) {
            float v = acc[r] + bias;
            int row = row0 + quad * 4 + r;
            int o = t * 16 + col;
            st_f32[row * 32 + o] = v;
            u16 hb = f2bf(v);
            st_hi[row * 32 + o] = hb;
            st_lo[row * 32 + o] = f2bf(v - bf2f(hb));
        }
    }
}

// ---------------------------------------------------------------------------
// Message + scatter kernel, round-1 structure (one wave per 16 edges, fully
// edge-parallel) but edges are DST-SORTED: atomics hit sequential agg lines
// (L2-local, write-back ~once) and equal-dst r-slots are merged in registers
// before issuing atomics (quad-uniform predicate).
// ---------------------------------------------------------------------------
__global__ __launch_bounds__(256) void msg_kernel(
    const u16* __restrict__ rbf, const u16* __restrict__ ew2f,
    const float* __restrict__ eb2, const float* __restrict__ state,
    const int* __restrict__ esrcp, const int* __restrict__ edstp,
    float* __restrict__ agg)
{
    __shared__ alignas(16) float eb2_lds[1024];
    __shared__ alignas(16) float ns_lds[4][16 * 68];   // [wave][e*68 + b*32 + h]
    int tid = threadIdx.x;
    {   // stage eb2 (block-wide)
        *(f32x4*)(eb2_lds + tid * 4) = *(const f32x4*)(eb2 + tid * 4);
    }
    int wave = tid >> 6, lane = tid & 63;
    int quad = lane >> 4, col = lane & 15;
    int e0 = (blockIdx.x * 4 + wave) * 16;   // sorted edge positions

    // A fragment: 16 edge rows x K=32 (sorted-order rbf, coalesced)
    s16x8 afrag = *(const s16x8*)(rbf + (size_t)(e0 + col) * 32 + quad * 8);

    // stage gathered node features: ns[e][b][h], e-stride 68
    {
        int el = lane >> 2, part = lane & 3;
        int b = part >> 1, half = part & 1;
        int src = esrcp[e0 + el];
        const float* sp = state + (size_t)(b * NNODES + src) * 32 + half * 16;
        float* dp = &ns_lds[wave][el * 68 + b * 32 + half * 16];
        *(f32x4*)(dp + 0)  = *(const f32x4*)(sp + 0);
        *(f32x4*)(dp + 4)  = *(const f32x4*)(sp + 4);
        *(f32x4*)(dp + 8)  = *(const f32x4*)(sp + 8);
        *(f32x4*)(dp + 12) = *(const f32x4*)(sp + 12);
    }
    int dstid[4];
#pragma unroll
    for (int r = 0; r < 4; ++r) dstid[r] = edstp[e0 + quad * 4 + r];
    __syncthreads();

    float msg[2][2][4] = {};   // [b][o-half][reg]
    const float* nsw = &ns_lds[wave][0];
#pragma unroll 4
    for (int hh = 0; hh < 16; ++hh) {
        int h0 = hh * 2, h1 = hh * 2 + 1;
        s16x8 b0 = *(const s16x8*)(ew2f + (4 * hh + 0) * 512 + lane * 8);
        s16x8 b1 = *(const s16x8*)(ew2f + (4 * hh + 1) * 512 + lane * 8);
        s16x8 b2 = *(const s16x8*)(ew2f + (4 * hh + 2) * 512 + lane * 8);
        s16x8 b3 = *(const s16x8*)(ew2f + (4 * hh + 3) * 512 + lane * 8);
        f32x4 z = {0,0,0,0};
        f32x4 d0 = __builtin_amdgcn_mfma_f32_16x16x32_bf16(afrag, b0, z, 0,0,0);
        f32x4 d1 = __builtin_amdgcn_mfma_f32_16x16x32_bf16(afrag, b1, z, 0,0,0);
        f32x4 d2 = __builtin_amdgcn_mfma_f32_16x16x32_bf16(afrag, b2, z, 0,0,0);
        f32x4 d3 = __builtin_amdgcn_mfma_f32_16x16x32_bf16(afrag, b3, z, 0,0,0);
        float e00 = eb2_lds[h0 * 32 + col],      e01 = eb2_lds[h0 * 32 + 16 + col];
        float e10 = eb2_lds[h1 * 32 + col],      e11 = eb2_lds[h1 * 32 + 16 + col];
#pragma unroll
        for (int r = 0; r < 4; ++r) {
            int e = quad * 4 + r;
            f32x2 n0v = *(const f32x2*)(nsw + e * 68 + 0 * 32 + h0);
            f32x2 n1v = *(const f32x2*)(nsw + e * 68 + 1 * 32 + h0);
            float w00 = d0[r] + e00, w01 = d1[r] + e01;
            float w10 = d2[r] + e10, w11 = d3[r] + e11;
            msg[0][0][r] += n0v.x * w00 + n0v.y * w10;
            msg[0][1][r] += n0v.x * w01 + n0v.y * w11;
            msg[1][0][r] += n1v.x * w00 + n1v.y * w10;
            msg[1][1][r] += n1v.x * w01 + n1v.y * w11;
        }
    }
    // merge r-slots with equal dst (quad-uniform, sorted edges make this common)
    bool valid[4] = {true, true, true, true};
#pragma unroll
    for (int r = 3; r >= 1; --r) {
        if (dstid[r] == dstid[r - 1]) {
            valid[r] = false;
            msg[0][0][r-1] += msg[0][0][r];
            msg[0][1][r-1] += msg[0][1][r];
            msg[1][0][r-1] += msg[1][0][r];
            msg[1][1][r-1] += msg[1][1][r];
        }
    }
#pragma unroll
    for (int r = 0; r < 4; ++r) {
        if (valid[r]) {
#pragma unroll
            for (int b = 0; b < 2; ++b) {
                float* base = agg + ((size_t)b * NNODES + dstid[r]) * 32;
                unsafeAtomicAdd(base + col,      msg[b][0][r]);
                unsafeAtomicAdd(base + 16 + col, msg[b][1][r]);
            }
        }
    }
}

// ---------------------------------------------------------------------------
// GRU step (unchanged).
// ---------------------------------------------------------------------------
__global__ __launch_bounds__(256) void gru_kernel(
    const float* __restrict__ agg, const float* __restrict__ conv_b,
    const float* __restrict__ st_f32, const u16* __restrict__ st_hi, const u16* __restrict__ st_lo,
    const u16* __restrict__ wihh, const u16* __restrict__ wihl,
    const u16* __restrict__ whhh, const u16* __restrict__ whhl,
    const float* __restrict__ b_ih, const float* __restrict__ b_hh,
    float* __restrict__ out_f32, u16* __restrict__ out_hi, u16* __restrict__ out_lo)
{
    int tid = threadIdx.x, wave = tid >> 6, lane = tid & 63;
    int quad = lane >> 4, col = lane & 15;
    int row0 = (blockIdx.x * 4 + wave) * 16;

    const float* ap = agg + (row0 + col) * 32 + quad * 8;
    f32x4 av0 = *(const f32x4*)(ap), av1 = *(const f32x4*)(ap + 4);
    const float* cb = conv_b + quad * 8;
    f32x4 cb0 = *(const f32x4*)(cb), cb1 = *(const f32x4*)(cb + 4);
    s16x8 anh, anl;
#pragma unroll
    for (int i = 0; i < 4; ++i) {
        float v0 = fmaxf(av0[i] + cb0[i], 0.f);
        float v1 = fmaxf(av1[i] + cb1[i], 0.f);
        u16 h0 = f2bf(v0); anh[i] = (short)h0;   anl[i] = (short)f2bf(v0 - bf2f(h0));
        u16 h1 = f2bf(v1); anh[4+i] = (short)h1; anl[4+i] = (short)f2bf(v1 - bf2f(h1));
    }
    s16x8 ahh = *(const s16x8*)(st_hi + (row0 + col) * 32 + quad * 8);
    s16x8 ahl = *(const s16x8*)(st_lo + (row0 + col) * 32 + quad * 8);

    f32x4 gx[6], gh[6];
#pragma unroll
    for (int t = 0; t < 6; ++t) {
        s16x8 bh = *(const s16x8*)(wihh + t * 512 + lane * 8);
        s16x8 bl = *(const s16x8*)(wihl + t * 512 + lane * 8);
        f32x4 acc = {0,0,0,0};
        acc = __builtin_amdgcn_mfma_f32_16x16x32_bf16(anl, bh, acc, 0,0,0);
        acc = __builtin_amdgcn_mfma_f32_16x16x32_bf16(anh, bl, acc, 0,0,0);
        acc = __builtin_amdgcn_mfma_f32_16x16x32_bf16(anh, bh, acc, 0,0,0);
        gx[t] = acc;
        s16x8 ch = *(const s16x8*)(whhh + t * 512 + lane * 8);
        s16x8 cl = *(const s16x8*)(whhl + t * 512 + lane * 8);
        f32x4 acc2 = {0,0,0,0};
        acc2 = __builtin_amdgcn_mfma_f32_16x16x32_bf16(ahl, ch, acc2, 0,0,0);
        acc2 = __builtin_amdgcn_mfma_f32_16x16x32_bf16(ahh, cl, acc2, 0,0,0);
        acc2 = __builtin_amdgcn_mfma_f32_16x16x32_bf16(ahh, ch, acc2, 0,0,0);
        gh[t] = acc2;
    }
    float bihv[6], bhhv[6];
#pragma unroll
    for (int t = 0; t < 6; ++t) { bihv[t] = b_ih[t * 16 + col]; bhhv[t] = b_hh[t * 16 + col]; }

#pragma unroll
    for (int r = 0; r < 4; ++r) {
        int row = row0 + quad * 4 + r;
#pragma unroll
        for (int oh = 0; oh < 2; ++oh) {
            int o = oh * 16 + col;
            float hid = st_f32[row * 32 + o];
            float sr = (gx[oh][r] + bihv[oh]) + (gh[oh][r] + bhhv[oh]);
            float sz = (gx[2+oh][r] + bihv[2+oh]) + (gh[2+oh][r] + bhhv[2+oh]);
            float gxn = gx[4+oh][r] + bihv[4+oh];
            float ghn = gh[4+oh][r] + bhhv[4+oh];
            float rr = 1.f / (1.f + __expf(-sr));
            float zz = 1.f / (1.f + __expf(-sz));
            float narg = gxn + rr * ghn;
            float ex = __expf(2.f * narg);
            float nn = (ex - 1.f) / (ex + 1.f);
            float hnew = (1.f - zz) * nn + zz * hid;
            out_f32[row * 32 + o] = hnew;
            u16 hb = f2bf(hnew);
            out_hi[row * 32 + o] = hb;
            out_lo[row * 32 + o] = f2bf(hnew - bf2f(hb));
        }
    }
}

// ---------------------------------------------------------------------------
extern "C" void kernel_launch(void* const* d_in, const int* in_sizes, int n_in,
                              void* d_out, int out_size, void* d_ws, size_t ws_size,
                              hipStream_t stream)
{
    const float* x      = (const float*)d_in[0];
    const float* er     = (const float*)d_in[1];
    const float* pw1    = (const float*)d_in[2];
    const float* pb1    = (const float*)d_in[3];
    const float* pw2    = (const float*)d_in[4];
    const float* pb2    = (const float*)d_in[5];
    const float* ew1    = (const float*)d_in[6];
    const float* eb1    = (const float*)d_in[7];
    const float* ew2    = (const float*)d_in[8];
    const float* eb2    = (const float*)d_in[9];
    const float* conv_b = (const float*)d_in[10];
    const float* wih    = (const float*)d_in[11];
    const float* whh    = (const float*)d_in[12];
    const float* bih    = (const float*)d_in[13];
    const float* bhh    = (const float*)d_in[14];
    const int*   esrc   = (const int*)d_in[15];
    const int*   edst   = (const int*)d_in[16];
    float* out = (float*)d_out;

    char* ws = (char*)d_ws;
    size_t off = 0;
    auto alloc = [&](size_t bytes) -> void* {
        void* p = ws + off;
        off = (off + bytes + 255) & ~(size_t)255;
        return p;
    };
    u16*   rbf    = (u16*)  alloc((size_t)(NEDGES + 16) * 32 * 2);
    float* st_f32 = (float*)alloc((size_t)ROWS * 32 * 4);
    u16*   st_hi  = (u16*)  alloc((size_t)ROWS * 32 * 2);
    u16*   st_lo  = (u16*)  alloc((size_t)ROWS * 32 * 2);
    float* agg    = (float*)alloc((size_t)ROWS * 32 * 4);
    u16*   ew2f   = (u16*)  alloc(64 * 512 * 2);
    u16*   pw1h   = (u16*)  alloc(2 * 512 * 2);
    u16*   pw1l   = (u16*)  alloc(2 * 512 * 2);
    u16*   pw2h   = (u16*)  alloc(2 * 512 * 2);
    u16*   pw2l   = (u16*)  alloc(2 * 512 * 2);
    u16*   wihhf  = (u16*)  alloc(6 * 512 * 2);
    u16*   wihlf  = (u16*)  alloc(6 * 512 * 2);
    u16*   whhhf  = (u16*)  alloc(6 * 512 * 2);
    u16*   whhlf  = (u16*)  alloc(6 * 512 * 2);
    // sort infrastructure
    int*   cnt      = (int*)alloc((size_t)NNODES * 4);
    int*   cursor   = (int*)alloc((size_t)NNODES * 4);
    int*   exc      = (int*)alloc((size_t)NNODES * 4);
    int*   bsum     = (int*)alloc(NBLK_SCAN * 4);
    int*   bofs     = (int*)alloc(NBLK_SCAN * 4);
    int*   rowstart = (int*)alloc((size_t)(NNODES + 1) * 4);
    int*   perm     = (int*)alloc((size_t)NEDGES * 4);
    int*   esrcp    = (int*)alloc((size_t)(NEDGES + 16) * 4);
    int*   edstp    = (int*)alloc((size_t)(NEDGES + 16) * 4);
    (void)in_sizes; (void)n_in; (void)out_size; (void)ws_size;

    // --- one-time: sort edges by dst ---
    hipMemsetAsync(cnt, 0, (size_t)NNODES * 4, stream);
    hipMemsetAsync(cursor, 0, (size_t)NNODES * 4, stream);
    hist_kernel<<<NEDGES / 256, 256, 0, stream>>>(edst, cnt);
    scan1_kernel<<<NBLK_SCAN, 256, 0, stream>>>(cnt, exc, bsum);
    scan2_kernel<<<1, 256, 0, stream>>>(bsum, bofs);
    scan3_kernel<<<NBLK_SCAN, 256, 0, stream>>>(exc, bofs, rowstart);
    scatter_kernel<<<NEDGES / 256, 256, 0, stream>>>(edst, esrc, rowstart, cursor,
                                                     perm, esrcp, edstp);

    pack_bfrag<<<128, 256, 0, stream>>>(ew2, ew2f, (u16*)nullptr, 64, 1024, 0);
    pack_bfrag<<<4,   256, 0, stream>>>(pw1, pw1h, pw1l, 2, 32, 0);
    pack_bfrag<<<4,   256, 0, stream>>>(pw2, pw2h, pw2l, 2, 32, 0);
    pack_bfrag<<<12,  256, 0, stream>>>(wih, wihhf, wihlf, 6, 96, 1);
    pack_bfrag<<<12,  256, 0, stream>>>(whh, whhhf, whhlf, 6, 96, 1);

    edgemlp_kernel<<<NEDGES / 8, 256, 0, stream>>>(er, ew1, eb1, perm, rbf);
    nodeproj_kernel<<<ROWS / 64, 256, 0, stream>>>(x, pw1h, pw1l, pb1, pw2h, pw2l, pb2,
                                                   st_f32, st_hi, st_lo);
    for (int s = 0; s < 3; ++s) {
        hipMemsetAsync(agg, 0, (size_t)ROWS * 32 * 4, stream);
        msg_kernel<<<NEDGES / 64, 256, 0, stream>>>(rbf, ew2f, eb2, st_f32,
                                                    esrcp, edstp, agg);
        float* of = (s == 2) ? out : st_f32;
        gru_kernel<<<ROWS / 64, 256, 0, stream>>>(agg, conv_b, st_f32, st_hi, st_lo,
                                                  wihhf, wihlf, whhhf, whhlf, bih, bhh,
                                                  of, st_hi, st_lo);
    }
}

// Round 4
// 379.365 us; speedup vs baseline: 1.7853x; 1.0195x over previous
//
#include <hip/hip_runtime.h>

typedef unsigned short u16;
typedef short s16x8 __attribute__((ext_vector_type(8)));
typedef float f32x4 __attribute__((ext_vector_type(4)));
typedef float f32x2 __attribute__((ext_vector_type(2)));

#define NNODES 55296
#define NEDGES 221184
#define ROWS   110592   // B * NNODES
#define NBLK_SCAN 216   // NNODES / 256

__device__ __forceinline__ u16 f2bf(float f) {
    union { float f; unsigned u; } v; v.f = f;
    unsigned r = (v.u + 0x7fffu + ((v.u >> 16) & 1u)) >> 16;
    return (u16)r;
}
__device__ __forceinline__ float bf2f(u16 u) {
    return __uint_as_float(((unsigned)u) << 16);
}

// ---------------------------------------------------------------------------
// Edge sorting by dst: histogram -> scan -> scatter (scan3/cursor folded away:
// scatter computes pos = exc[d] + bofs[d>>8] + (atomicSub(cnt[d])-1)).
// ---------------------------------------------------------------------------
__global__ __launch_bounds__(256) void hist_kernel(
    const int* __restrict__ edst, int* __restrict__ cnt)
{
    int i = blockIdx.x * 256 + threadIdx.x;
    atomicAdd(&cnt[edst[i]], 1);
}

__global__ __launch_bounds__(256) void scan1_kernel(
    const int* __restrict__ cnt, int* __restrict__ exc, int* __restrict__ bsum)
{
    __shared__ int s[256];
    int t = threadIdx.x, g = blockIdx.x * 256 + t;
    int v = cnt[g];
    s[t] = v; __syncthreads();
#pragma unroll
    for (int d = 1; d < 256; d <<= 1) {
        int x = (t >= d) ? s[t - d] : 0;
        __syncthreads();
        s[t] += x;
        __syncthreads();
    }
    exc[g] = s[t] - v;
    if (t == 255) bsum[blockIdx.x] = s[255];
}

__global__ __launch_bounds__(256) void scan2_kernel(
    const int* __restrict__ bsum, int* __restrict__ bofs)
{
    __shared__ int s[256];
    int t = threadIdx.x;
    int v = (t < NBLK_SCAN) ? bsum[t] : 0;
    s[t] = v; __syncthreads();
#pragma unroll
    for (int d = 1; d < 256; d <<= 1) {
        int x = (t >= d) ? s[t - d] : 0;
        __syncthreads();
        s[t] += x;
        __syncthreads();
    }
    if (t < NBLK_SCAN) bofs[t] = s[t] - v;
}

__global__ __launch_bounds__(256) void scatter_kernel(
    const int* __restrict__ edst, const int* __restrict__ esrc,
    const int* __restrict__ exc, const int* __restrict__ bofs,
    int* __restrict__ cnt,
    int* __restrict__ perm, int* __restrict__ esrcp, int* __restrict__ edstp)
{
    int i = blockIdx.x * 256 + threadIdx.x;
    int d = edst[i];
    int slot = atomicSub(&cnt[d], 1) - 1;
    int pos = exc[d] + bofs[d >> 8] + slot;
    perm[pos] = i;
    esrcp[pos] = esrc[i];
    edstp[pos] = d;
}

// ---------------------------------------------------------------------------
// All weight packs fused into one dispatch. Segments by blockIdx:
// [0,128) ew2 | [128,132) pw1 | [132,136) pw2 | [136,148) wih | [148,160) whh
// ---------------------------------------------------------------------------
__global__ __launch_bounds__(256) void pack_all(
    const float* __restrict__ ew2, u16* __restrict__ ew2f,
    const float* __restrict__ pw1, u16* __restrict__ pw1h, u16* __restrict__ pw1l,
    const float* __restrict__ pw2, u16* __restrict__ pw2h, u16* __restrict__ pw2l,
    const float* __restrict__ wih, u16* __restrict__ wihh, u16* __restrict__ wihl,
    const float* __restrict__ whh, u16* __restrict__ whhh, u16* __restrict__ whhl)
{
    int b = blockIdx.x;
    const float* src; u16 *hi, *lo; int ncols, trans, base;
    if (b < 128)      { src = ew2; hi = ew2f; lo = nullptr; ncols = 1024; trans = 0; base = 0;   }
    else if (b < 132) { src = pw1; hi = pw1h; lo = pw1l;    ncols = 32;   trans = 0; base = 128; }
    else if (b < 136) { src = pw2; hi = pw2h; lo = pw2l;    ncols = 32;   trans = 0; base = 132; }
    else if (b < 148) { src = wih; hi = wihh; lo = wihl;    ncols = 96;   trans = 1; base = 136; }
    else              { src = whh; hi = whhh; lo = whhl;    ncols = 96;   trans = 1; base = 148; }
    int idx = (b - base) * 256 + threadIdx.x;
    int t = idx >> 9, rr = idx & 511, lane = rr >> 3, j = rr & 7;
    int k = (lane >> 4) * 8 + j;
    int n = t * 16 + (lane & 15);
    float v = trans ? src[n * 32 + k] : src[k * ncols + n];
    u16 hb = f2bf(v);
    hi[idx] = hb;
    if (lo) lo[idx] = f2bf(v - bf2f(hb));
}

// ---------------------------------------------------------------------------
// Edge MLP layer 1, writing rbf in DST-SORTED edge order (reads er via perm).
// ---------------------------------------------------------------------------
__global__ __launch_bounds__(256) void edgemlp_kernel(
    const float* __restrict__ er, const float* __restrict__ ew1,
    const float* __restrict__ eb1, const int* __restrict__ perm,
    u16* __restrict__ rbf)
{
    __shared__ float er_lds[32];
    __shared__ float w_lds[128];
    __shared__ float b_lds[32];
    int tid = threadIdx.x;
    int e8 = blockIdx.x * 8;   // sorted position base
    if (tid < 32) {
        int e = perm[e8 + (tid >> 2)];
        er_lds[tid] = er[e * 4 + (tid & 3)];
    }
    else if (tid < 160) w_lds[tid - 32] = ew1[tid - 32];
    else if (tid < 192) b_lds[tid - 160] = eb1[tid - 160];
    __syncthreads();
    int el = tid >> 5, o = tid & 31;
    const float* e4 = er_lds + el * 4;
    float v = b_lds[o] + e4[0] * w_lds[o] + e4[1] * w_lds[32 + o]
                       + e4[2] * w_lds[64 + o] + e4[3] * w_lds[96 + o];
    rbf[(e8 + el) * 32 + o] = f2bf(fmaxf(v, 0.f));
}

// ---------------------------------------------------------------------------
// Node projection (unchanged): h0 = relu(x@pw1+pb1)@pw2+pb2.
// ---------------------------------------------------------------------------
__global__ __launch_bounds__(256) void nodeproj_kernel(
    const float* __restrict__ x,
    const u16* __restrict__ pw1h, const u16* __restrict__ pw1l, const float* __restrict__ pb1,
    const u16* __restrict__ pw2h, const u16* __restrict__ pw2l, const float* __restrict__ pb2,
    float* __restrict__ st_f32, u16* __restrict__ st_hi, u16* __restrict__ st_lo)
{
    __shared__ alignas(16) u16 t_hi[4][512];
    __shared__ alignas(16) u16 t_lo[4][512];
    int tid = threadIdx.x, wave = tid >> 6, lane = tid & 63;
    int quad = lane >> 4, col = lane & 15;
    int row0 = (blockIdx.x * 4 + wave) * 16;

    const float* xp = x + (row0 + col) * 32 + quad * 8;
    f32x4 xv0 = *(const f32x4*)(xp), xv1 = *(const f32x4*)(xp + 4);
    s16x8 ah, al;
#pragma unroll
    for (int i = 0; i < 4; ++i) {
        u16 h0 = f2bf(xv0[i]); ah[i] = (short)h0; al[i] = (short)f2bf(xv0[i] - bf2f(h0));
        u16 h1 = f2bf(xv1[i]); ah[4+i] = (short)h1; al[4+i] = (short)f2bf(xv1[i] - bf2f(h1));
    }
#pragma unroll
    for (int t = 0; t < 2; ++t) {
        s16x8 bh = *(const s16x8*)(pw1h + t * 512 + lane * 8);
        s16x8 bl = *(const s16x8*)(pw1l + t * 512 + lane * 8);
        f32x4 acc = {0,0,0,0};
        acc = __builtin_amdgcn_mfma_f32_16x16x32_bf16(al, bh, acc, 0,0,0);
        acc = __builtin_amdgcn_mfma_f32_16x16x32_bf16(ah, bl, acc, 0,0,0);
        acc = __builtin_amdgcn_mfma_f32_16x16x32_bf16(ah, bh, acc, 0,0,0);
        float bias = pb1[t * 16 + col];
#pragma unroll
        for (int r = 0; r < 4; ++r) {
            float v = fmaxf(acc[r] + bias, 0.f);
            u16 hb = f2bf(v);
            int idx = (quad * 4 + r) * 32 + t * 16 + col;
            t_hi[wave][idx] = hb;
            t_lo[wave][idx] = f2bf(v - bf2f(hb));
        }
    }
    __syncthreads();
    s16x8 th = *(const s16x8*)(&t_hi[wave][col * 32 + quad * 8]);
    s16x8 tl = *(const s16x8*)(&t_lo[wave][col * 32 + quad * 8]);
#pragma unroll
    for (int t = 0; t < 2; ++t) {
        s16x8 bh = *(const s16x8*)(pw2h + t * 512 + lane * 8);
        s16x8 bl = *(const s16x8*)(pw2l + t * 512 + lane * 8);
        f32x4 acc = {0,0,0,0};
        acc = __builtin_amdgcn_mfma_f32_16x16x32_bf16(tl, bh, acc, 0,0,0);
        acc = __builtin_amdgcn_mfma_f32_16x16x32_bf16(th, bl, acc, 0,0,0);
        acc = __builtin_amdgcn_mfma_f32_16x16x32_bf16(th, bh, acc, 0,0,0);
        float bias = pb2[t * 16 + col];
#pragma unroll
        for (int r = 0; r < 4; ++r) {
            float v = acc[r] + bias;
            int row = row0 + quad * 4 + r;
            int o = t * 16 + col;
            st_f32[row * 32 + o] = v;
            u16 hb = f2bf(v);
            st_hi[row * 32 + o] = hb;
            st_lo[row * 32 + o] = f2bf(v - bf2f(hb));
        }
    }
}

// ---------------------------------------------------------------------------
// Message + scatter kernel v4: 32 edges per wave (2 MFMA subtiles sharing each
// weight fragment), batch-interleaved LDS ns[e][h*2+b] so one ds_read_b128
// yields (b0,b1)x(h0,h1) and the epilogue runs as f32x2 packed math over the
// batch dim. Dst-sorted atomics + quad-local merge as round 3.
// ---------------------------------------------------------------------------
__global__ __launch_bounds__(256) void msg_kernel(
    const u16* __restrict__ rbf, const u16* __restrict__ ew2f,
    const float* __restrict__ eb2, const float* __restrict__ state,
    const int* __restrict__ esrcp, const int* __restrict__ edstp,
    float* __restrict__ agg)
{
    __shared__ alignas(16) float eb2_lds[1024];
    __shared__ alignas(16) float ns_lds[4][32 * 68];   // [wave][e*68 + h*2 + b]
    int tid = threadIdx.x;
    {   // stage eb2 (block-wide)
        *(f32x4*)(eb2_lds + tid * 4) = *(const f32x4*)(eb2 + tid * 4);
    }
    int wave = tid >> 6, lane = tid & 63;
    int quad = lane >> 4, col = lane & 15;
    int e0 = (blockIdx.x * 4 + wave) * 32;   // sorted edge positions

    // A fragments: 2 subtiles of 16 edges x K=32
    s16x8 afrag0 = *(const s16x8*)(rbf + (size_t)(e0 + col) * 32 + quad * 8);
    s16x8 afrag1 = *(const s16x8*)(rbf + (size_t)(e0 + 16 + col) * 32 + quad * 8);

    // stage gathered node features batch-interleaved: ns[e][h*2+b]
#pragma unroll
    for (int i = 0; i < 2; ++i) {
        int t2 = i * 64 + lane;
        int el = t2 >> 2, hc = t2 & 3;          // edge-local 0..31, h-chunk of 8
        int src = esrcp[e0 + el];
        const float* s0 = state + (size_t)src * 32 + hc * 8;
        const float* s1 = state + ((size_t)NNODES + src) * 32 + hc * 8;
        f32x4 a0 = *(const f32x4*)(s0),     a1 = *(const f32x4*)(s0 + 4);
        f32x4 c0 = *(const f32x4*)(s1),     c1 = *(const f32x4*)(s1 + 4);
        float* dp = &ns_lds[wave][el * 68 + hc * 16];
        f32x4 w0 = {a0.x, c0.x, a0.y, c0.y};
        f32x4 w1 = {a0.z, c0.z, a0.w, c0.w};
        f32x4 w2 = {a1.x, c1.x, a1.y, c1.y};
        f32x4 w3 = {a1.z, c1.z, a1.w, c1.w};
        *(f32x4*)(dp + 0)  = w0;
        *(f32x4*)(dp + 4)  = w1;
        *(f32x4*)(dp + 8)  = w2;
        *(f32x4*)(dp + 12) = w3;
    }
    int dstid[8];
#pragma unroll
    for (int g = 0; g < 2; ++g)
#pragma unroll
        for (int r = 0; r < 4; ++r)
            dstid[g * 4 + r] = edstp[e0 + g * 16 + quad * 4 + r];
    __syncthreads();

    f32x2 m[2][2][4];   // [subtile g][o-half][reg], f32x2 over batch (b0,b1)
#pragma unroll
    for (int g = 0; g < 2; ++g)
#pragma unroll
        for (int oh = 0; oh < 2; ++oh)
#pragma unroll
            for (int r = 0; r < 4; ++r) m[g][oh][r] = f32x2{0.f, 0.f};

    const float* nsw = &ns_lds[wave][0];
#pragma unroll 2
    for (int hh = 0; hh < 16; ++hh) {
        int h0 = hh * 2, h1 = hh * 2 + 1;
        s16x8 b0 = *(const s16x8*)(ew2f + (4 * hh + 0) * 512 + lane * 8);
        s16x8 b1 = *(const s16x8*)(ew2f + (4 * hh + 1) * 512 + lane * 8);
        s16x8 b2 = *(const s16x8*)(ew2f + (4 * hh + 2) * 512 + lane * 8);
        s16x8 b3 = *(const s16x8*)(ew2f + (4 * hh + 3) * 512 + lane * 8);
        f32x4 z = {0,0,0,0};
        f32x4 d[2][4];
        d[0][0] = __builtin_amdgcn_mfma_f32_16x16x32_bf16(afrag0, b0, z, 0,0,0);
        d[0][1] = __builtin_amdgcn_mfma_f32_16x16x32_bf16(afrag0, b1, z, 0,0,0);
        d[0][2] = __builtin_amdgcn_mfma_f32_16x16x32_bf16(afrag0, b2, z, 0,0,0);
        d[0][3] = __builtin_amdgcn_mfma_f32_16x16x32_bf16(afrag0, b3, z, 0,0,0);
        d[1][0] = __builtin_amdgcn_mfma_f32_16x16x32_bf16(afrag1, b0, z, 0,0,0);
        d[1][1] = __builtin_amdgcn_mfma_f32_16x16x32_bf16(afrag1, b1, z, 0,0,0);
        d[1][2] = __builtin_amdgcn_mfma_f32_16x16x32_bf16(afrag1, b2, z, 0,0,0);
        d[1][3] = __builtin_amdgcn_mfma_f32_16x16x32_bf16(afrag1, b3, z, 0,0,0);
        float e00 = eb2_lds[h0 * 32 + col],  e01 = eb2_lds[h0 * 32 + 16 + col];
        float e10 = eb2_lds[h1 * 32 + col],  e11 = eb2_lds[h1 * 32 + 16 + col];
#pragma unroll
        for (int g = 0; g < 2; ++g) {
#pragma unroll
            for (int r = 0; r < 4; ++r) {
                int e = g * 16 + quad * 4 + r;
                f32x4 nv = *(const f32x4*)(nsw + e * 68 + hh * 4); // (b0h0,b1h0,b0h1,b1h1)
                f32x2 nh0 = {nv.x, nv.y};
                f32x2 nh1 = {nv.z, nv.w};
                float w00 = d[g][0][r] + e00, w01 = d[g][1][r] + e01;
                float w10 = d[g][2][r] + e10, w11 = d[g][3][r] + e11;
                m[g][0][r] += nh0 * w00 + nh1 * w10;
                m[g][1][r] += nh0 * w01 + nh1 * w11;
            }
        }
    }
    // merge r-slots with equal dst (quad-uniform; sorted edges make this common)
#pragma unroll
    for (int g = 0; g < 2; ++g) {
        bool valid[4] = {true, true, true, true};
#pragma unroll
        for (int r = 3; r >= 1; --r) {
            if (dstid[g * 4 + r] == dstid[g * 4 + r - 1]) {
                valid[r] = false;
                m[g][0][r-1] += m[g][0][r];
                m[g][1][r-1] += m[g][1][r];
            }
        }
#pragma unroll
        for (int r = 0; r < 4; ++r) {
            if (valid[r]) {
                float* p0 = agg + (size_t)dstid[g * 4 + r] * 32;
                float* p1 = agg + ((size_t)NNODES + dstid[g * 4 + r]) * 32;
                unsafeAtomicAdd(p0 + col,      m[g][0][r].x);
                unsafeAtomicAdd(p0 + 16 + col, m[g][1][r].x);
                unsafeAtomicAdd(p1 + col,      m[g][0][r].y);
                unsafeAtomicAdd(p1 + 16 + col, m[g][1][r].y);
            }
        }
    }
}

// ---------------------------------------------------------------------------
// GRU step (unchanged).
// ---------------------------------------------------------------------------
__global__ __launch_bounds__(256) void gru_kernel(
    const float* __restrict__ agg, const float* __restrict__ conv_b,
    const float* __restrict__ st_f32, const u16* __restrict__ st_hi, const u16* __restrict__ st_lo,
    const u16* __restrict__ wihh, const u16* __restrict__ wihl,
    const u16* __restrict__ whhh, const u16* __restrict__ whhl,
    const float* __restrict__ b_ih, const float* __restrict__ b_hh,
    float* __restrict__ out_f32, u16* __restrict__ out_hi, u16* __restrict__ out_lo)
{
    int tid = threadIdx.x, wave = tid >> 6, lane = tid & 63;
    int quad = lane >> 4, col = lane & 15;
    int row0 = (blockIdx.x * 4 + wave) * 16;

    const float* ap = agg + (row0 + col) * 32 + quad * 8;
    f32x4 av0 = *(const f32x4*)(ap), av1 = *(const f32x4*)(ap + 4);
    const float* cb = conv_b + quad * 8;
    f32x4 cb0 = *(const f32x4*)(cb), cb1 = *(const f32x4*)(cb + 4);
    s16x8 anh, anl;
#pragma unroll
    for (int i = 0; i < 4; ++i) {
        float v0 = fmaxf(av0[i] + cb0[i], 0.f);
        float v1 = fmaxf(av1[i] + cb1[i], 0.f);
        u16 h0 = f2bf(v0); anh[i] = (short)h0;   anl[i] = (short)f2bf(v0 - bf2f(h0));
        u16 h1 = f2bf(v1); anh[4+i] = (short)h1; anl[4+i] = (short)f2bf(v1 - bf2f(h1));
    }
    s16x8 ahh = *(const s16x8*)(st_hi + (row0 + col) * 32 + quad * 8);
    s16x8 ahl = *(const s16x8*)(st_lo + (row0 + col) * 32 + quad * 8);

    f32x4 gx[6], gh[6];
#pragma unroll
    for (int t = 0; t < 6; ++t) {
        s16x8 bh = *(const s16x8*)(wihh + t * 512 + lane * 8);
        s16x8 bl = *(const s16x8*)(wihl + t * 512 + lane * 8);
        f32x4 acc = {0,0,0,0};
        acc = __builtin_amdgcn_mfma_f32_16x16x32_bf16(anl, bh, acc, 0,0,0);
        acc = __builtin_amdgcn_mfma_f32_16x16x32_bf16(anh, bl, acc, 0,0,0);
        acc = __builtin_amdgcn_mfma_f32_16x16x32_bf16(anh, bh, acc, 0,0,0);
        gx[t] = acc;
        s16x8 ch = *(const s16x8*)(whhh + t * 512 + lane * 8);
        s16x8 cl = *(const s16x8*)(whhl + t * 512 + lane * 8);
        f32x4 acc2 = {0,0,0,0};
        acc2 = __builtin_amdgcn_mfma_f32_16x16x32_bf16(ahl, ch, acc2, 0,0,0);
        acc2 = __builtin_amdgcn_mfma_f32_16x16x32_bf16(ahh, cl, acc2, 0,0,0);
        acc2 = __builtin_amdgcn_mfma_f32_16x16x32_bf16(ahh, ch, acc2, 0,0,0);
        gh[t] = acc2;
    }
    float bihv[6], bhhv[6];
#pragma unroll
    for (int t = 0; t < 6; ++t) { bihv[t] = b_ih[t * 16 + col]; bhhv[t] = b_hh[t * 16 + col]; }

#pragma unroll
    for (int r = 0; r < 4; ++r) {
        int row = row0 + quad * 4 + r;
#pragma unroll
        for (int oh = 0; oh < 2; ++oh) {
            int o = oh * 16 + col;
            float hid = st_f32[row * 32 + o];
            float sr = (gx[oh][r] + bihv[oh]) + (gh[oh][r] + bhhv[oh]);
            float sz = (gx[2+oh][r] + bihv[2+oh]) + (gh[2+oh][r] + bhhv[2+oh]);
            float gxn = gx[4+oh][r] + bihv[4+oh];
            float ghn = gh[4+oh][r] + bhhv[4+oh];
            float rr = 1.f / (1.f + __expf(-sr));
            float zz = 1.f / (1.f + __expf(-sz));
            float narg = gxn + rr * ghn;
            float ex = __expf(2.f * narg);
            float nn = (ex - 1.f) / (ex + 1.f);
            float hnew = (1.f - zz) * nn + zz * hid;
            out_f32[row * 32 + o] = hnew;
            u16 hb = f2bf(hnew);
            out_hi[row * 32 + o] = hb;
            out_lo[row * 32 + o] = f2bf(hnew - bf2f(hb));
        }
    }
}

// ---------------------------------------------------------------------------
extern "C" void kernel_launch(void* const* d_in, const int* in_sizes, int n_in,
                              void* d_out, int out_size, void* d_ws, size_t ws_size,
                              hipStream_t stream)
{
    const float* x      = (const float*)d_in[0];
    const float* er     = (const float*)d_in[1];
    const float* pw1    = (const float*)d_in[2];
    const float* pb1    = (const float*)d_in[3];
    const float* pw2    = (const float*)d_in[4];
    const float* pb2    = (const float*)d_in[5];
    const float* ew1    = (const float*)d_in[6];
    const float* eb1    = (const float*)d_in[7];
    const float* ew2    = (const float*)d_in[8];
    const float* eb2    = (const float*)d_in[9];
    const float* conv_b = (const float*)d_in[10];
    const float* wih    = (const float*)d_in[11];
    const float* whh    = (const float*)d_in[12];
    const float* bih    = (const float*)d_in[13];
    const float* bhh    = (const float*)d_in[14];
    const int*   esrc   = (const int*)d_in[15];
    const int*   edst   = (const int*)d_in[16];
    float* out = (float*)d_out;

    char* ws = (char*)d_ws;
    size_t off = 0;
    auto alloc = [&](size_t bytes) -> void* {
        void* p = ws + off;
        off = (off + bytes + 255) & ~(size_t)255;
        return p;
    };
    u16*   rbf    = (u16*)  alloc((size_t)(NEDGES + 32) * 32 * 2);
    float* st_f32 = (float*)alloc((size_t)ROWS * 32 * 4);
    u16*   st_hi  = (u16*)  alloc((size_t)ROWS * 32 * 2);
    u16*   st_lo  = (u16*)  alloc((size_t)ROWS * 32 * 2);
    float* agg    = (float*)alloc((size_t)ROWS * 32 * 4);
    u16*   ew2f   = (u16*)  alloc(64 * 512 * 2);
    u16*   pw1h   = (u16*)  alloc(2 * 512 * 2);
    u16*   pw1l   = (u16*)  alloc(2 * 512 * 2);
    u16*   pw2h   = (u16*)  alloc(2 * 512 * 2);
    u16*   pw2l   = (u16*)  alloc(2 * 512 * 2);
    u16*   wihhf  = (u16*)  alloc(6 * 512 * 2);
    u16*   wihlf  = (u16*)  alloc(6 * 512 * 2);
    u16*   whhhf  = (u16*)  alloc(6 * 512 * 2);
    u16*   whhlf  = (u16*)  alloc(6 * 512 * 2);
    // sort infrastructure
    int*   cnt      = (int*)alloc((size_t)NNODES * 4);
    int*   exc      = (int*)alloc((size_t)NNODES * 4);
    int*   bsum     = (int*)alloc(NBLK_SCAN * 4);
    int*   bofs     = (int*)alloc(NBLK_SCAN * 4);
    int*   perm     = (int*)alloc((size_t)NEDGES * 4);
    int*   esrcp    = (int*)alloc((size_t)(NEDGES + 32) * 4);
    int*   edstp    = (int*)alloc((size_t)(NEDGES + 32) * 4);
    (void)in_sizes; (void)n_in; (void)out_size; (void)ws_size;

    // --- one-time: sort edges by dst ---
    hipMemsetAsync(cnt, 0, (size_t)NNODES * 4, stream);
    hist_kernel<<<NEDGES / 256, 256, 0, stream>>>(edst, cnt);
    scan1_kernel<<<NBLK_SCAN, 256, 0, stream>>>(cnt, exc, bsum);
    scan2_kernel<<<1, 256, 0, stream>>>(bsum, bofs);
    scatter_kernel<<<NEDGES / 256, 256, 0, stream>>>(edst, esrc, exc, bofs, cnt,
                                                     perm, esrcp, edstp);

    pack_all<<<160, 256, 0, stream>>>(ew2, ew2f, pw1, pw1h, pw1l, pw2, pw2h, pw2l,
                                      wih, wihhf, wihlf, whh, whhhf, whhlf);

    edgemlp_kernel<<<NEDGES / 8, 256, 0, stream>>>(er, ew1, eb1, perm, rbf);
    nodeproj_kernel<<<ROWS / 64, 256, 0, stream>>>(x, pw1h, pw1l, pb1, pw2h, pw2l, pb2,
                                                   st_f32, st_hi, st_lo);
    for (int s = 0; s < 3; ++s) {
        hipMemsetAsync(agg, 0, (size_t)ROWS * 32 * 4, stream);
        msg_kernel<<<NEDGES / 128, 256, 0, stream>>>(rbf, ew2f, eb2, st_f32,
                                                     esrcp, edstp, agg);
        float* of = (s == 2) ? out : st_f32;
        gru_kernel<<<ROWS / 64, 256, 0, stream>>>(agg, conv_b, st_f32, st_hi, st_lo,
                                                  wihhf, wihlf, whhhf, whhlf, bih, bhh,
                                                  of, st_hi, st_lo);
    }
}